// Round 4
// baseline (652.218 us; speedup 1.0000x reference)
//
#include <hip/hip_runtime.h>
#include <stdint.h>
#include <math.h>

#define NAG 8192
#define NB  144          // 128 feats + deg col(128) + pad to 9*16
#define BM  32           // M rows per block
#define LDA 72           // LDS row stride (shorts) for A tile (64 + 8 pad)
#define LDB 72           // LDS row stride for B tile
#define NSPLIT 4         // K splits (private partials, no atomics)

typedef __attribute__((ext_vector_type(8))) short short8;
typedef __attribute__((ext_vector_type(4))) float floatx4;

__device__ __forceinline__ float bf2f(unsigned short u) {
    union { uint32_t i; float f; } v; v.i = ((uint32_t)u) << 16; return v.f;
}
__device__ __forceinline__ unsigned short f2bf(float f) {
    union { float f; uint32_t i; } v; v.f = f;
    uint32_t x = v.i;
    return (unsigned short)((x + 0x7FFFu + ((x >> 16) & 1u)) >> 16);  // RNE
}

// ---------------- Kernel 0: detect float storage dtype from W1 raw bits ----------------
__global__ __launch_bounds__(64) void k0_init(
    int* __restrict__ flag, const unsigned short* __restrict__ W1raw)
{
    int big = 0;
    #pragma unroll
    for (int j = 0; j < 8; ++j) {
        float v = bf2f(W1raw[threadIdx.x * 8 + j]);
        if (!(fabsf(v) <= 1e6f)) big = 1;   // catches huge and NaN (fp32 mantissa noise)
    }
    unsigned long long m = __ballot(big);
    if (threadIdx.x == 0) *flag = (m != 0ull) ? 1 : 0;
}

// ---------------- Kernel 1: h = tanh(obs@W1+b1); write h_f32 and hT_bf16 ----------------
__global__ __launch_bounds__(256) void k1_encode(
    const void* __restrict__ obs,   // [8192][64] fp32 or bf16
    const void* __restrict__ W1,    // [64][128]
    const void* __restrict__ b1,    // [128]
    const int* __restrict__ flag,
    float* __restrict__ h_f32,      // [8192][128]
    unsigned short* __restrict__ hT)// [144][8192] bf16 (row128=ones, 129..143=0)
{
    __shared__ float obs_lds[32][68];
    __shared__ unsigned short ht_lds[128][33];
    const int t = threadIdx.x;
    const int abase = blockIdx.x * 32;
    const bool isf = (*flag != 0);

    {   // stage obs tile 32x64, 8 scalar elems/thread
        int a = t >> 3, c0 = (t & 7) * 8;
        if (isf) {
            const float* p = (const float*)obs;
            #pragma unroll
            for (int j = 0; j < 8; ++j)
                obs_lds[a][c0 + j] = p[(size_t)(abase + a) * 64 + c0 + j];
        } else {
            const unsigned short* p = (const unsigned short*)obs;
            #pragma unroll
            for (int j = 0; j < 8; ++j)
                obs_lds[a][c0 + j] = bf2f(p[(size_t)(abase + a) * 64 + c0 + j]);
        }
    }
    __syncthreads();

    const int o = t & 127;
    const int half = t >> 7;          // wave-uniform
    float acc[16];
    if (isf) {
        const float* Wp = (const float*)W1;
        float bias = ((const float*)b1)[o];
        #pragma unroll
        for (int i = 0; i < 16; ++i) acc[i] = bias;
        for (int k0 = 0; k0 < 64; k0 += 8) {
            float w[8];
            #pragma unroll
            for (int j = 0; j < 8; ++j) w[j] = Wp[(k0 + j) * 128 + o];
            #pragma unroll
            for (int j = 0; j < 8; ++j)
                #pragma unroll
                for (int i = 0; i < 16; ++i)
                    acc[i] = fmaf(obs_lds[half * 16 + i][k0 + j], w[j], acc[i]);
        }
    } else {
        const unsigned short* Wp = (const unsigned short*)W1;
        float bias = bf2f(((const unsigned short*)b1)[o]);
        #pragma unroll
        for (int i = 0; i < 16; ++i) acc[i] = bias;
        for (int k0 = 0; k0 < 64; k0 += 8) {
            float w[8];
            #pragma unroll
            for (int j = 0; j < 8; ++j) w[j] = bf2f(Wp[(k0 + j) * 128 + o]);
            #pragma unroll
            for (int j = 0; j < 8; ++j)
                #pragma unroll
                for (int i = 0; i < 16; ++i)
                    acc[i] = fmaf(obs_lds[half * 16 + i][k0 + j], w[j], acc[i]);
        }
    }
    #pragma unroll
    for (int i = 0; i < 16; ++i) {
        float th = tanhf(acc[i]);
        int a = half * 16 + i;
        h_f32[(size_t)(abase + a) * 128 + o] = th;
        ht_lds[o][a] = f2bf(th);
    }
    __syncthreads();

    for (int p = 0; p < 18; ++p) {
        int n = p * 8 + (t >> 5);
        int a = t & 31;
        unsigned short v;
        if (n < 128)       v = ht_lds[n][a];
        else if (n == 128) v = 0x3F80;     // 1.0 bf16 -> deg column
        else               v = 0;
        hT[(size_t)n * NAG + abase + a] = v;
    }
}

// ---------------- Kernel 2: Cpart[ks] = adj[:, kslice] @ [h|1|0]  (bf16 MFMA, depth-2 A prefetch) ----------------
__global__ __launch_bounds__(256, 4) void k2_msggemm(
    const int* __restrict__ adj,              // [8192][8192] int32 {0,1}
    const unsigned short* __restrict__ hT,    // [144][8192] bf16
    float* __restrict__ Cpart)                // [NSPLIT][8192][144] fp32 (fully overwritten)
{
    __shared__ __align__(16) unsigned short Alds[BM * LDA];
    __shared__ __align__(16) unsigned short Blds[NB * LDB];
    const int t = threadIdx.x;
    const int mtile = blockIdx.x & 255;       // 256 M-tiles of 32 rows
    const int ks = blockIdx.x >> 8;           // 4 K-splits of 2048
    const int row0 = mtile * BM;
    const int kbeg = ks * 2048;

    const int wave = t >> 6, lane = t & 63;
    const int fm = lane & 15, quad = lane >> 4;
    const int mh = (wave >> 1) * 16;          // M half per wave pair
    const int ntbase = (wave & 1) * 5;        // N tiles: waves even 0..4, odd 5..8
    const int ntc = (wave & 1) ? 4 : 5;

    floatx4 acc[5];
    #pragma unroll
    for (int i = 0; i < 5; ++i) acc[i] = (floatx4)0.f;

    const int ar = t >> 3, aq = t & 7;        // A staging: 32 rows x (8 chunks of 8 ints)
    const int bln = t & 7, brow = t >> 3;     // B staging: chunk-in-row, row-offset

    const int* aP = adj + (size_t)(row0 + ar) * NAG + aq * 8;
    int4 rA0[2], rA1[2];
    uint4 rB[5];

#define LOADA(R, K) do { \
        (R)[0] = *reinterpret_cast<const int4*>(aP + (K));      \
        (R)[1] = *reinterpret_cast<const int4*>(aP + (K) + 4);  \
    } while (0)
#define LOADB(K) do { \
        _Pragma("unroll") \
        for (int p = 0; p < 5; ++p) { \
            int n = p * 32 + brow; \
            if (n < NB) rB[p] = *reinterpret_cast<const uint4*>(hT + (size_t)n * NAG + (K) + bln * 8); \
        } \
    } while (0)
#define STOREA(R) do { \
        _Pragma("unroll") \
        for (int c = 0; c < 2; ++c) { \
            uint32_t d0 = ((uint32_t)(R)[c].x | ((uint32_t)(R)[c].y << 16)) * 0x3F80u; \
            uint32_t d1 = ((uint32_t)(R)[c].z | ((uint32_t)(R)[c].w << 16)) * 0x3F80u; \
            *reinterpret_cast<uint2*>(&Alds[ar * LDA + aq * 8 + c * 4]) = make_uint2(d0, d1); \
        } \
    } while (0)
#define STOREB() do { \
        _Pragma("unroll") \
        for (int p = 0; p < 5; ++p) { \
            int n = p * 32 + brow; \
            if (n < NB) *reinterpret_cast<uint4*>(&Blds[n * LDB + bln * 8]) = rB[p]; \
        } \
    } while (0)
#define COMPUTE() do { \
        _Pragma("unroll") \
        for (int kk = 0; kk < 64; kk += 32) { \
            short8 af = *reinterpret_cast<const short8*>(&Alds[(mh + fm) * LDA + kk + quad * 8]); \
            for (int j = 0; j < ntc; ++j) { \
                short8 bf = *reinterpret_cast<const short8*>(&Blds[((ntbase + j) * 16 + fm) * LDB + kk + quad * 8]); \
                acc[j] = __builtin_amdgcn_mfma_f32_16x16x32_bf16(af, bf, acc[j], 0, 0, 0); \
            } \
        } \
    } while (0)

    // preamble: A two tiles ahead, B one tile ahead
    LOADA(rA0, kbeg);
    LOADA(rA1, kbeg + 64);
    LOADB(kbeg);

    for (int it = 0; it < 32; it += 2) {
        // even step: consumes rA0 (tile it), rB (tile it)
        __syncthreads();
        STOREA(rA0);
        STOREB();
        __syncthreads();
        if (it + 1 < 32) LOADB(kbeg + (it + 1) * 64);     // B before A: keeps depth-2 A in flight
        if (it + 2 < 32) LOADA(rA0, kbeg + (it + 2) * 64);
        COMPUTE();
        // odd step: consumes rA1 (tile it+1), rB (tile it+1)
        __syncthreads();
        STOREA(rA1);
        STOREB();
        __syncthreads();
        if (it + 2 < 32) LOADB(kbeg + (it + 2) * 64);
        if (it + 3 < 32) LOADA(rA1, kbeg + (it + 3) * 64);
        COMPUTE();
    }

    // epilogue: C/D layout col=lane&15, row=quad*4+reg; private partial per K-split
    float* out = Cpart + (size_t)ks * (NAG * NB);
    #pragma unroll
    for (int j = 0; j < 5; ++j) {
        if (j < ntc) {
            int col = (ntbase + j) * 16 + fm;
            #pragma unroll
            for (int r = 0; r < 4; ++r) {
                int row = row0 + mh + quad * 4 + r;
                out[(size_t)row * NB + col] = acc[j][r];
            }
        }
    }
#undef LOADA
#undef LOADB
#undef STOREA
#undef STOREB
#undef COMPUTE
}

// ---------------- Kernel 3: reduce partials, msg=sum/deg, actor MLP, dtype-adaptive ----------------
__global__ __launch_bounds__(256) void k3_actor(
    const float* __restrict__ h_f32,          // [8192][128]
    const float* __restrict__ Cpart,          // [NSPLIT][8192][144] fp32
    const void* __restrict__ W2,              // [256][128]
    const void* __restrict__ b2,              // [128]
    const void* __restrict__ W3,              // [128][16]
    const void* __restrict__ b3,              // [16]
    const int* __restrict__ flag,
    void* __restrict__ out)                   // [8192][16]
{
    __shared__ float comb[32][256];
    __shared__ float hid[32][132];
    __shared__ float inv_lds[32];
    const int t = threadIdx.x;
    const int abase = blockIdx.x * 32;
    const bool isf = (*flag != 0);
    const size_t PS = (size_t)NAG * NB;

    if (t < 32) {
        float deg = 0.f;
        #pragma unroll
        for (int s = 0; s < NSPLIT; ++s)
            deg += Cpart[s * PS + (size_t)(abase + t) * NB + 128];
        inv_lds[t] = 1.0f / fmaxf(deg, 1.0f);
    }
    __syncthreads();
    // h part (32 agents x 32 float4), parallel staging
    #pragma unroll
    for (int j = 0; j < 4; ++j) {
        int idx = j * 256 + t, a = idx >> 5, c = idx & 31;
        float4 v = *reinterpret_cast<const float4*>(h_f32 + (size_t)(abase + a) * 128 + c * 4);
        *reinterpret_cast<float4*>(&comb[a][c * 4]) = v;
    }
    // msg part: sum 4 partials, scale by 1/deg
    #pragma unroll
    for (int j = 0; j < 4; ++j) {
        int idx = j * 256 + t, a = idx >> 5, c = idx & 31;
        float4 v = make_float4(0.f, 0.f, 0.f, 0.f);
        #pragma unroll
        for (int s = 0; s < NSPLIT; ++s) {
            float4 p = *reinterpret_cast<const float4*>(Cpart + s * PS + (size_t)(abase + a) * NB + c * 4);
            v.x += p.x; v.y += p.y; v.z += p.z; v.w += p.w;
        }
        float sc = inv_lds[a];
        v.x *= sc; v.y *= sc; v.z *= sc; v.w *= sc;
        *reinterpret_cast<float4*>(&comb[a][128 + c * 4]) = v;
    }
    __syncthreads();

    const int o = t & 127, half = t >> 7;
    float acc[16];
    if (isf) {
        const float* Wp = (const float*)W2;
        float bias = ((const float*)b2)[o];
        #pragma unroll
        for (int i = 0; i < 16; ++i) acc[i] = bias;
        for (int c0 = 0; c0 < 256; c0 += 8) {
            float w[8];
            #pragma unroll
            for (int j = 0; j < 8; ++j) w[j] = Wp[(c0 + j) * 128 + o];
            #pragma unroll
            for (int j = 0; j < 8; ++j)
                #pragma unroll
                for (int i = 0; i < 16; ++i)
                    acc[i] = fmaf(comb[half * 16 + i][c0 + j], w[j], acc[i]);
        }
    } else {
        const unsigned short* Wp = (const unsigned short*)W2;
        float bias = bf2f(((const unsigned short*)b2)[o]);
        #pragma unroll
        for (int i = 0; i < 16; ++i) acc[i] = bias;
        for (int c0 = 0; c0 < 256; c0 += 8) {
            float w[8];
            #pragma unroll
            for (int j = 0; j < 8; ++j) w[j] = bf2f(Wp[(c0 + j) * 128 + o]);
            #pragma unroll
            for (int j = 0; j < 8; ++j)
                #pragma unroll
                for (int i = 0; i < 16; ++i)
                    acc[i] = fmaf(comb[half * 16 + i][c0 + j], w[j], acc[i]);
        }
    }
    #pragma unroll
    for (int i = 0; i < 16; ++i)
        hid[half * 16 + i][o] = tanhf(acc[i]);
    __syncthreads();

    const int q = t & 15, ar = t >> 4;   // agents ar and ar+16
    float l0, l1;
    if (isf) {
        const float* Wp = (const float*)W3;
        l0 = ((const float*)b3)[q]; l1 = l0;
        #pragma unroll 4
        for (int oo = 0; oo < 128; ++oo) {
            float w = Wp[oo * 16 + q];
            l0 = fmaf(hid[ar][oo], w, l0);
            l1 = fmaf(hid[ar + 16][oo], w, l1);
        }
    } else {
        const unsigned short* Wp = (const unsigned short*)W3;
        l0 = bf2f(((const unsigned short*)b3)[q]); l1 = l0;
        #pragma unroll 4
        for (int oo = 0; oo < 128; ++oo) {
            float w = bf2f(Wp[oo * 16 + q]);
            l0 = fmaf(hid[ar][oo], w, l0);
            l1 = fmaf(hid[ar + 16][oo], w, l1);
        }
    }
    size_t i0 = (size_t)(abase + ar) * 16 + q;
    size_t i1 = (size_t)(abase + ar + 16) * 16 + q;
    if (isf) {
        ((float*)out)[i0] = l0;
        ((float*)out)[i1] = l1;
    } else {
        ((unsigned short*)out)[i0] = f2bf(l0);
        ((unsigned short*)out)[i1] = f2bf(l1);
    }
}

extern "C" void kernel_launch(void* const* d_in, const int* in_sizes, int n_in,
                              void* d_out, int out_size, void* d_ws, size_t ws_size,
                              hipStream_t stream) {
    const void* obs = d_in[0];
    const int*  adj = (const int*)d_in[1];
    const void* W1  = d_in[2];
    const void* b1  = d_in[3];
    const void* W2  = d_in[4];
    const void* b2  = d_in[5];
    const void* W3  = d_in[6];
    const void* b3  = d_in[7];

    char* ws = (char*)d_ws;
    unsigned short* hT = (unsigned short*)(ws);                 // 2,359,296 B
    float* h_f32 = (float*)(ws + 2359296);                      // 4,194,304 B
    float* Cpart = (float*)(ws + 2359296 + 4194304);            // 4 x 4,718,592 = 18,874,368 B
    int*   flag  = (int*)(ws + 2359296 + 4194304 + 18874368);   // 4 B  (total 25.4 MB)

    hipLaunchKernelGGL(k0_init, dim3(1), dim3(64), 0, stream, flag, (const unsigned short*)W1);
    hipLaunchKernelGGL(k1_encode, dim3(256), dim3(256), 0, stream, obs, W1, b1, flag, h_f32, hT);
    hipLaunchKernelGGL(k2_msggemm, dim3(1024), dim3(256), 0, stream, adj, hT, Cpart);
    hipLaunchKernelGGL(k3_actor, dim3(256), dim3(256), 0, stream, h_f32, Cpart, W2, b2, W3, b3, flag, d_out);
}

// Round 5
// 645.763 us; speedup vs baseline: 1.0100x; 1.0100x over previous
//
#include <hip/hip_runtime.h>
#include <stdint.h>
#include <math.h>

#define NAG 8192
#define NB  144          // 128 feats + deg col(128) + pad to 9*16
#define BM  32           // M rows per block
#define LDA 72           // LDS row stride (shorts) for A tile (64 + 8 pad)
#define LDB 72           // LDS row stride for B tile
#define NSPLIT 4         // K splits (private partials, no atomics)

typedef __attribute__((ext_vector_type(8))) short short8;
typedef __attribute__((ext_vector_type(4))) float floatx4;

__device__ __forceinline__ float bf2f(unsigned short u) {
    union { uint32_t i; float f; } v; v.i = ((uint32_t)u) << 16; return v.f;
}
__device__ __forceinline__ unsigned short f2bf(float f) {
    union { float f; uint32_t i; } v; v.f = f;
    uint32_t x = v.i;
    return (unsigned short)((x + 0x7FFFu + ((x >> 16) & 1u)) >> 16);  // RNE
}

// ---------------- Kernel 0: detect float storage dtype from W1 raw bits ----------------
__global__ __launch_bounds__(64) void k0_init(
    int* __restrict__ flag, const unsigned short* __restrict__ W1raw)
{
    int big = 0;
    #pragma unroll
    for (int j = 0; j < 8; ++j) {
        float v = bf2f(W1raw[threadIdx.x * 8 + j]);
        if (!(fabsf(v) <= 1e6f)) big = 1;   // catches huge and NaN (fp32 mantissa noise)
    }
    unsigned long long m = __ballot(big);
    if (threadIdx.x == 0) *flag = (m != 0ull) ? 1 : 0;
}

// ---------------- Kernel 1: h = tanh(obs@W1+b1); write h_f32 and hT_bf16 ----------------
__global__ __launch_bounds__(256) void k1_encode(
    const void* __restrict__ obs,   // [8192][64] fp32 or bf16
    const void* __restrict__ W1,    // [64][128]
    const void* __restrict__ b1,    // [128]
    const int* __restrict__ flag,
    float* __restrict__ h_f32,      // [8192][128]
    unsigned short* __restrict__ hT)// [144][8192] bf16 (row128=ones, 129..143=0)
{
    __shared__ float obs_lds[32][68];
    __shared__ unsigned short ht_lds[128][33];
    const int t = threadIdx.x;
    const int abase = blockIdx.x * 32;
    const bool isf = (*flag != 0);

    {   // stage obs tile 32x64, 8 scalar elems/thread
        int a = t >> 3, c0 = (t & 7) * 8;
        if (isf) {
            const float* p = (const float*)obs;
            #pragma unroll
            for (int j = 0; j < 8; ++j)
                obs_lds[a][c0 + j] = p[(size_t)(abase + a) * 64 + c0 + j];
        } else {
            const unsigned short* p = (const unsigned short*)obs;
            #pragma unroll
            for (int j = 0; j < 8; ++j)
                obs_lds[a][c0 + j] = bf2f(p[(size_t)(abase + a) * 64 + c0 + j]);
        }
    }
    __syncthreads();

    const int o = t & 127;
    const int half = t >> 7;          // wave-uniform
    float acc[16];
    if (isf) {
        const float* Wp = (const float*)W1;
        float bias = ((const float*)b1)[o];
        #pragma unroll
        for (int i = 0; i < 16; ++i) acc[i] = bias;
        for (int k0 = 0; k0 < 64; k0 += 8) {
            float w[8];
            #pragma unroll
            for (int j = 0; j < 8; ++j) w[j] = Wp[(k0 + j) * 128 + o];
            #pragma unroll
            for (int j = 0; j < 8; ++j)
                #pragma unroll
                for (int i = 0; i < 16; ++i)
                    acc[i] = fmaf(obs_lds[half * 16 + i][k0 + j], w[j], acc[i]);
        }
    } else {
        const unsigned short* Wp = (const unsigned short*)W1;
        float bias = bf2f(((const unsigned short*)b1)[o]);
        #pragma unroll
        for (int i = 0; i < 16; ++i) acc[i] = bias;
        for (int k0 = 0; k0 < 64; k0 += 8) {
            float w[8];
            #pragma unroll
            for (int j = 0; j < 8; ++j) w[j] = bf2f(Wp[(k0 + j) * 128 + o]);
            #pragma unroll
            for (int j = 0; j < 8; ++j)
                #pragma unroll
                for (int i = 0; i < 16; ++i)
                    acc[i] = fmaf(obs_lds[half * 16 + i][k0 + j], w[j], acc[i]);
        }
    }
    #pragma unroll
    for (int i = 0; i < 16; ++i) {
        float th = tanhf(acc[i]);
        int a = half * 16 + i;
        h_f32[(size_t)(abase + a) * 128 + o] = th;
        ht_lds[o][a] = f2bf(th);
    }
    __syncthreads();

    for (int p = 0; p < 18; ++p) {
        int n = p * 8 + (t >> 5);
        int a = t & 31;
        unsigned short v;
        if (n < 128)       v = ht_lds[n][a];
        else if (n == 128) v = 0x3F80;     // 1.0 bf16 -> deg column
        else               v = 0;
        hT[(size_t)n * NAG + abase + a] = v;
    }
}

// ---------------- Kernel 2: Cpart[ks] = adj[:, kslice] @ [h|1|0] ----------------
// bf16 MFMA; depth-2 A register prefetch; ALL register-array indices compile-time
// (round-4 lesson: runtime loop bound ntc demoted acc[] to scratch -> 537 MB spill traffic).
__global__ __launch_bounds__(256, 4) void k2_msggemm(
    const int* __restrict__ adj,              // [8192][8192] int32 {0,1}
    const unsigned short* __restrict__ hT,    // [144][8192] bf16
    float* __restrict__ Cpart)                // [NSPLIT][8192][144] fp32 (fully overwritten)
{
    __shared__ __align__(16) unsigned short Alds[BM * LDA];
    __shared__ __align__(16) unsigned short Blds[NB * LDB];
    const int t = threadIdx.x;
    const int mtile = blockIdx.x & 255;       // 256 M-tiles of 32 rows
    const int ks = blockIdx.x >> 8;           // 4 K-splits of 2048
    const int row0 = mtile * BM;
    const int kbeg = ks * 2048;

    const int wave = t >> 6, lane = t & 63;
    const int fm = lane & 15, quad = lane >> 4;
    const int mh = (wave >> 1) * 16;          // M half per wave pair
    const int ntbase = (wave & 1) * 5;        // N tiles: even waves 0..4, odd waves 5..8

    floatx4 acc[5];
    #pragma unroll
    for (int i = 0; i < 5; ++i) acc[i] = (floatx4)0.f;

    const int ar = t >> 3, aq = t & 7;        // A staging: 32 rows x (8 chunks of 8 ints)
    const int bln = t & 7, brow = t >> 3;     // B staging: chunk-in-row, row-offset

    const int* aP = adj + (size_t)(row0 + ar) * NAG + aq * 8;
    int4 rA0[2], rA1[2];
    uint4 rB[5];

#define LOADA(R, K) do { \
        (R)[0] = *reinterpret_cast<const int4*>(aP + (K));      \
        (R)[1] = *reinterpret_cast<const int4*>(aP + (K) + 4);  \
    } while (0)
#define LOADB(K) do { \
        _Pragma("unroll") \
        for (int p = 0; p < 5; ++p) { \
            int n = p * 32 + brow; \
            if (n < NB) rB[p] = *reinterpret_cast<const uint4*>(hT + (size_t)n * NAG + (K) + bln * 8); \
        } \
    } while (0)
#define STOREA(R) do { \
        _Pragma("unroll") \
        for (int c = 0; c < 2; ++c) { \
            uint32_t d0 = ((uint32_t)(R)[c].x | ((uint32_t)(R)[c].y << 16)) * 0x3F80u; \
            uint32_t d1 = ((uint32_t)(R)[c].z | ((uint32_t)(R)[c].w << 16)) * 0x3F80u; \
            *reinterpret_cast<uint2*>(&Alds[ar * LDA + aq * 8 + c * 4]) = make_uint2(d0, d1); \
        } \
    } while (0)
#define STOREB() do { \
        _Pragma("unroll") \
        for (int p = 0; p < 5; ++p) { \
            int n = p * 32 + brow; \
            if (n < NB) *reinterpret_cast<uint4*>(&Blds[n * LDB + bln * 8]) = rB[p]; \
        } \
    } while (0)
#define COMPUTE() do { \
        _Pragma("unroll") \
        for (int kk = 0; kk < 64; kk += 32) { \
            short8 af = *reinterpret_cast<const short8*>(&Alds[(mh + fm) * LDA + kk + quad * 8]); \
            _Pragma("unroll") \
            for (int j = 0; j < 5; ++j) { \
                if (ntbase + j < 9) { /* wave-uniform; j compile-time -> acc stays in VGPRs */ \
                    short8 bf = *reinterpret_cast<const short8*>(&Blds[((ntbase + j) * 16 + fm) * LDB + kk + quad * 8]); \
                    acc[j] = __builtin_amdgcn_mfma_f32_16x16x32_bf16(af, bf, acc[j], 0, 0, 0); \
                } \
            } \
        } \
    } while (0)

    // preamble: A two tiles ahead, B one tile ahead
    LOADA(rA0, kbeg);
    LOADA(rA1, kbeg + 64);
    LOADB(kbeg);

    for (int it = 0; it < 32; it += 2) {
        // even step: consumes rA0 (tile it), rB (tile it)
        __syncthreads();
        STOREA(rA0);
        STOREB();
        __syncthreads();
        if (it + 1 < 32) LOADB(kbeg + (it + 1) * 64);     // B first: keeps depth-2 A in flight
        if (it + 2 < 32) LOADA(rA0, kbeg + (it + 2) * 64);
        COMPUTE();
        // odd step: consumes rA1 (tile it+1), rB (tile it+1)
        __syncthreads();
        STOREA(rA1);
        STOREB();
        __syncthreads();
        if (it + 2 < 32) LOADB(kbeg + (it + 2) * 64);
        if (it + 3 < 32) LOADA(rA1, kbeg + (it + 3) * 64);
        COMPUTE();
    }

    // epilogue: C/D layout col=lane&15, row=quad*4+reg; private partial per K-split
    float* out = Cpart + (size_t)ks * (NAG * NB);
    #pragma unroll
    for (int j = 0; j < 5; ++j) {
        if (ntbase + j < 9) {
            int col = (ntbase + j) * 16 + fm;
            #pragma unroll
            for (int r = 0; r < 4; ++r) {
                int row = row0 + mh + quad * 4 + r;
                out[(size_t)row * NB + col] = acc[j][r];
            }
        }
    }
#undef LOADA
#undef LOADB
#undef STOREA
#undef STOREB
#undef COMPUTE
}

// ---------------- Kernel 3: reduce partials, msg=sum/deg, actor MLP, dtype-adaptive ----------------
__global__ __launch_bounds__(256) void k3_actor(
    const float* __restrict__ h_f32,          // [8192][128]
    const float* __restrict__ Cpart,          // [NSPLIT][8192][144] fp32
    const void* __restrict__ W2,              // [256][128]
    const void* __restrict__ b2,              // [128]
    const void* __restrict__ W3,              // [128][16]
    const void* __restrict__ b3,              // [16]
    const int* __restrict__ flag,
    void* __restrict__ out)                   // [8192][16]
{
    __shared__ float comb[32][256];
    __shared__ float hid[32][132];
    __shared__ float inv_lds[32];
    const int t = threadIdx.x;
    const int abase = blockIdx.x * 32;
    const bool isf = (*flag != 0);
    const size_t PS = (size_t)NAG * NB;

    if (t < 32) {
        float deg = 0.f;
        #pragma unroll
        for (int s = 0; s < NSPLIT; ++s)
            deg += Cpart[s * PS + (size_t)(abase + t) * NB + 128];
        inv_lds[t] = 1.0f / fmaxf(deg, 1.0f);
    }
    __syncthreads();
    // h part (32 agents x 32 float4), parallel staging
    #pragma unroll
    for (int j = 0; j < 4; ++j) {
        int idx = j * 256 + t, a = idx >> 5, c = idx & 31;
        float4 v = *reinterpret_cast<const float4*>(h_f32 + (size_t)(abase + a) * 128 + c * 4);
        *reinterpret_cast<float4*>(&comb[a][c * 4]) = v;
    }
    // msg part: sum 4 partials, scale by 1/deg
    #pragma unroll
    for (int j = 0; j < 4; ++j) {
        int idx = j * 256 + t, a = idx >> 5, c = idx & 31;
        float4 v = make_float4(0.f, 0.f, 0.f, 0.f);
        #pragma unroll
        for (int s = 0; s < NSPLIT; ++s) {
            float4 p = *reinterpret_cast<const float4*>(Cpart + s * PS + (size_t)(abase + a) * NB + c * 4);
            v.x += p.x; v.y += p.y; v.z += p.z; v.w += p.w;
        }
        float sc = inv_lds[a];
        v.x *= sc; v.y *= sc; v.z *= sc; v.w *= sc;
        *reinterpret_cast<float4*>(&comb[a][128 + c * 4]) = v;
    }
    __syncthreads();

    const int o = t & 127, half = t >> 7;
    float acc[16];
    if (isf) {
        const float* Wp = (const float*)W2;
        float bias = ((const float*)b2)[o];
        #pragma unroll
        for (int i = 0; i < 16; ++i) acc[i] = bias;
        for (int c0 = 0; c0 < 256; c0 += 8) {
            float w[8];
            #pragma unroll
            for (int j = 0; j < 8; ++j) w[j] = Wp[(c0 + j) * 128 + o];
            #pragma unroll
            for (int j = 0; j < 8; ++j)
                #pragma unroll
                for (int i = 0; i < 16; ++i)
                    acc[i] = fmaf(comb[half * 16 + i][c0 + j], w[j], acc[i]);
        }
    } else {
        const unsigned short* Wp = (const unsigned short*)W2;
        float bias = bf2f(((const unsigned short*)b2)[o]);
        #pragma unroll
        for (int i = 0; i < 16; ++i) acc[i] = bias;
        for (int c0 = 0; c0 < 256; c0 += 8) {
            float w[8];
            #pragma unroll
            for (int j = 0; j < 8; ++j) w[j] = bf2f(Wp[(c0 + j) * 128 + o]);
            #pragma unroll
            for (int j = 0; j < 8; ++j)
                #pragma unroll
                for (int i = 0; i < 16; ++i)
                    acc[i] = fmaf(comb[half * 16 + i][c0 + j], w[j], acc[i]);
        }
    }
    #pragma unroll
    for (int i = 0; i < 16; ++i)
        hid[half * 16 + i][o] = tanhf(acc[i]);
    __syncthreads();

    const int q = t & 15, ar = t >> 4;   // agents ar and ar+16
    float l0, l1;
    if (isf) {
        const float* Wp = (const float*)W3;
        l0 = ((const float*)b3)[q]; l1 = l0;
        #pragma unroll 4
        for (int oo = 0; oo < 128; ++oo) {
            float w = Wp[oo * 16 + q];
            l0 = fmaf(hid[ar][oo], w, l0);
            l1 = fmaf(hid[ar + 16][oo], w, l1);
        }
    } else {
        const unsigned short* Wp = (const unsigned short*)W3;
        l0 = bf2f(((const unsigned short*)b3)[q]); l1 = l0;
        #pragma unroll 4
        for (int oo = 0; oo < 128; ++oo) {
            float w = bf2f(Wp[oo * 16 + q]);
            l0 = fmaf(hid[ar][oo], w, l0);
            l1 = fmaf(hid[ar + 16][oo], w, l1);
        }
    }
    size_t i0 = (size_t)(abase + ar) * 16 + q;
    size_t i1 = (size_t)(abase + ar + 16) * 16 + q;
    if (isf) {
        ((float*)out)[i0] = l0;
        ((float*)out)[i1] = l1;
    } else {
        ((unsigned short*)out)[i0] = f2bf(l0);
        ((unsigned short*)out)[i1] = f2bf(l1);
    }
}

extern "C" void kernel_launch(void* const* d_in, const int* in_sizes, int n_in,
                              void* d_out, int out_size, void* d_ws, size_t ws_size,
                              hipStream_t stream) {
    const void* obs = d_in[0];
    const int*  adj = (const int*)d_in[1];
    const void* W1  = d_in[2];
    const void* b1  = d_in[3];
    const void* W2  = d_in[4];
    const void* b2  = d_in[5];
    const void* W3  = d_in[6];
    const void* b3  = d_in[7];

    char* ws = (char*)d_ws;
    unsigned short* hT = (unsigned short*)(ws);                 // 2,359,296 B
    float* h_f32 = (float*)(ws + 2359296);                      // 4,194,304 B
    float* Cpart = (float*)(ws + 2359296 + 4194304);            // 4 x 4,718,592 = 18,874,368 B
    int*   flag  = (int*)(ws + 2359296 + 4194304 + 18874368);   // 4 B  (total 25.4 MB)

    hipLaunchKernelGGL(k0_init, dim3(1), dim3(64), 0, stream, flag, (const unsigned short*)W1);
    hipLaunchKernelGGL(k1_encode, dim3(256), dim3(256), 0, stream, obs, W1, b1, flag, h_f32, hT);
    hipLaunchKernelGGL(k2_msggemm, dim3(1024), dim3(256), 0, stream, adj, hT, Cpart);
    hipLaunchKernelGGL(k3_actor, dim3(256), dim3(256), 0, stream, h_f32, Cpart, W2, b2, W3, b3, flag, d_out);
}

// Round 6
// 502.597 us; speedup vs baseline: 1.2977x; 1.2849x over previous
//
#include <hip/hip_runtime.h>
#include <stdint.h>
#include <math.h>

#define NAG 8192
#define NB  144          // Cpart row stride: 128 feats + deg col(128) + pad
#define BM  64           // M rows per block
#define LDA 72           // LDS row stride (shorts) for A tile (64 + 8 pad)
#define LDB 72           // LDS row stride for B tile
#define NBROWS 160       // B LDS rows: 10 N-tiles of 16 (tile 9 = zeros, discarded)
#define NSPLIT 4         // K splits (private partials, no atomics)

typedef __attribute__((ext_vector_type(8))) short short8;
typedef __attribute__((ext_vector_type(4))) float floatx4;

__device__ __forceinline__ float bf2f(unsigned short u) {
    union { uint32_t i; float f; } v; v.i = ((uint32_t)u) << 16; return v.f;
}
__device__ __forceinline__ unsigned short f2bf(float f) {
    union { float f; uint32_t i; } v; v.f = f;
    uint32_t x = v.i;
    return (unsigned short)((x + 0x7FFFu + ((x >> 16) & 1u)) >> 16);  // RNE
}

// ---------------- Kernel 0: detect float storage dtype from W1 raw bits ----------------
__global__ __launch_bounds__(64) void k0_init(
    int* __restrict__ flag, const unsigned short* __restrict__ W1raw)
{
    int big = 0;
    #pragma unroll
    for (int j = 0; j < 8; ++j) {
        float v = bf2f(W1raw[threadIdx.x * 8 + j]);
        if (!(fabsf(v) <= 1e6f)) big = 1;   // catches huge and NaN (fp32 mantissa noise)
    }
    unsigned long long m = __ballot(big);
    if (threadIdx.x == 0) *flag = (m != 0ull) ? 1 : 0;
}

// ---------------- Kernel 1: h = tanh(obs@W1+b1); write h_f32 and hT_bf16 ----------------
__global__ __launch_bounds__(256) void k1_encode(
    const void* __restrict__ obs,   // [8192][64] fp32 or bf16
    const void* __restrict__ W1,    // [64][128]
    const void* __restrict__ b1,    // [128]
    const int* __restrict__ flag,
    float* __restrict__ h_f32,      // [8192][128]
    unsigned short* __restrict__ hT)// [144][8192] bf16 (row128=ones, 129..143=0)
{
    __shared__ float obs_lds[32][68];
    __shared__ unsigned short ht_lds[128][33];
    const int t = threadIdx.x;
    const int abase = blockIdx.x * 32;
    const bool isf = (*flag != 0);

    {   // stage obs tile 32x64, 8 scalar elems/thread
        int a = t >> 3, c0 = (t & 7) * 8;
        if (isf) {
            const float* p = (const float*)obs;
            #pragma unroll
            for (int j = 0; j < 8; ++j)
                obs_lds[a][c0 + j] = p[(size_t)(abase + a) * 64 + c0 + j];
        } else {
            const unsigned short* p = (const unsigned short*)obs;
            #pragma unroll
            for (int j = 0; j < 8; ++j)
                obs_lds[a][c0 + j] = bf2f(p[(size_t)(abase + a) * 64 + c0 + j]);
        }
    }
    __syncthreads();

    const int o = t & 127;
    const int half = t >> 7;          // wave-uniform
    float acc[16];
    if (isf) {
        const float* Wp = (const float*)W1;
        float bias = ((const float*)b1)[o];
        #pragma unroll
        for (int i = 0; i < 16; ++i) acc[i] = bias;
        for (int k0 = 0; k0 < 64; k0 += 8) {
            float w[8];
            #pragma unroll
            for (int j = 0; j < 8; ++j) w[j] = Wp[(k0 + j) * 128 + o];
            #pragma unroll
            for (int j = 0; j < 8; ++j)
                #pragma unroll
                for (int i = 0; i < 16; ++i)
                    acc[i] = fmaf(obs_lds[half * 16 + i][k0 + j], w[j], acc[i]);
        }
    } else {
        const unsigned short* Wp = (const unsigned short*)W1;
        float bias = bf2f(((const unsigned short*)b1)[o]);
        #pragma unroll
        for (int i = 0; i < 16; ++i) acc[i] = bias;
        for (int k0 = 0; k0 < 64; k0 += 8) {
            float w[8];
            #pragma unroll
            for (int j = 0; j < 8; ++j) w[j] = bf2f(Wp[(k0 + j) * 128 + o]);
            #pragma unroll
            for (int j = 0; j < 8; ++j)
                #pragma unroll
                for (int i = 0; i < 16; ++i)
                    acc[i] = fmaf(obs_lds[half * 16 + i][k0 + j], w[j], acc[i]);
        }
    }
    #pragma unroll
    for (int i = 0; i < 16; ++i) {
        float th = tanhf(acc[i]);
        int a = half * 16 + i;
        h_f32[(size_t)(abase + a) * 128 + o] = th;
        ht_lds[o][a] = f2bf(th);
    }
    __syncthreads();

    for (int p = 0; p < 18; ++p) {
        int n = p * 8 + (t >> 5);
        int a = t & 31;
        unsigned short v;
        if (n < 128)       v = ht_lds[n][a];
        else if (n == 128) v = 0x3F80;     // 1.0 bf16 -> deg column
        else               v = 0;
        hT[(size_t)n * NAG + abase + a] = v;
    }
}

// ---------------- Kernel 2: Cpart[ks] = adj[:, kslice] @ [h|1|0] ----------------
// 512 threads, 8 waves: wave = strip(0..3) x nhalf(0..1). B LDS padded to 160 rows so
// EVERY wave does exactly 5 N-tiles -> zero conditionals in the K-loop (rounds 4/5:
// wave-asymmetric guarded MFMA caused scratch spill, 540 MB HBM writes).
__global__ __launch_bounds__(512, 4) void k2_msggemm(
    const int* __restrict__ adj,              // [8192][8192] int32 {0,1}
    const unsigned short* __restrict__ hT,    // [144][8192] bf16
    float* __restrict__ Cpart,                // [NSPLIT][8192][144] fp32
    float* __restrict__ dump)                 // scrap for tile-9 stores
{
    __shared__ __align__(16) unsigned short Alds[BM * LDA];      //  9216 B
    __shared__ __align__(16) unsigned short Blds[NBROWS * LDB];  // 23040 B
    const int t = threadIdx.x;
    const int mtile = blockIdx.x & 127;       // 128 M-tiles of 64 rows
    const int ks = blockIdx.x >> 7;           // 4 K-splits of 2048
    const int row0 = mtile * BM;
    const int kbeg = ks * 2048;

    const int wave = t >> 6, lane = t & 63;
    const int fm = lane & 15, quad = lane >> 4;
    const int strip = wave & 3;               // M strip (16 rows)
    const int nhalf = wave >> 2;              // N half (tiles nhalf*5 .. nhalf*5+4)

    floatx4 acc[5];
    #pragma unroll
    for (int i = 0; i < 5; ++i) acc[i] = (floatx4)0.f;

    // A staging: 64 rows x 64 ints; thread -> row ar, 8-int chunk aq
    const int ar = t >> 3, aq = t & 7;
    // B staging: 128 rows x 64 shorts; thread -> row br, 16-short chunk bq
    const int br = t >> 2, bq = t & 3;

    const int* aP = adj + (size_t)(row0 + ar) * NAG + aq * 8;
    const unsigned short* bP = hT + (size_t)br * NAG + bq * 16;
    int4 rA[2];
    uint4 rB[2];

    // constant B rows 128..159: row 128 = 1.0 (deg), 129..159 = 0. Written ONCE.
    {
        int crow = 128 + (t >> 4);
        int ccol = (t & 15) * 4;
        uint32_t v = (crow == 128) ? 0x3F803F80u : 0u;
        *reinterpret_cast<uint2*>(&Blds[crow * LDB + ccol]) = make_uint2(v, v);
    }

#define LOADAB(K) do { \
        rA[0] = *reinterpret_cast<const int4*>(aP + (K)); \
        rA[1] = *reinterpret_cast<const int4*>(aP + (K) + 4); \
        rB[0] = *reinterpret_cast<const uint4*>(bP + (K)); \
        rB[1] = *reinterpret_cast<const uint4*>(bP + (K) + 8); \
    } while (0)
#define STOREAB() do { \
        _Pragma("unroll") \
        for (int c = 0; c < 2; ++c) { \
            uint32_t d0 = ((uint32_t)rA[c].x | ((uint32_t)rA[c].y << 16)) * 0x3F80u; \
            uint32_t d1 = ((uint32_t)rA[c].z | ((uint32_t)rA[c].w << 16)) * 0x3F80u; \
            *reinterpret_cast<uint2*>(&Alds[ar * LDA + aq * 8 + c * 4]) = make_uint2(d0, d1); \
        } \
        *reinterpret_cast<uint4*>(&Blds[br * LDB + bq * 16]) = rB[0]; \
        *reinterpret_cast<uint4*>(&Blds[br * LDB + bq * 16 + 8]) = rB[1]; \
    } while (0)

    LOADAB(kbeg);   // depth-1 prefetch preamble

    for (int it = 0; it < 32; ++it) {
        __syncthreads();   // previous compute done before LDS overwrite
        STOREAB();
        __syncthreads();
        if (it + 1 < 32) LOADAB(kbeg + (it + 1) * 64);   // next tile in flight during compute
        #pragma unroll
        for (int kk = 0; kk < 64; kk += 32) {
            short8 af = *reinterpret_cast<const short8*>(&Alds[(strip * 16 + fm) * LDA + kk + quad * 8]);
            #pragma unroll
            for (int j = 0; j < 5; ++j) {   // unconditional: tile 9 = zero rows
                short8 bf = *reinterpret_cast<const short8*>(&Blds[((nhalf * 5 + j) * 16 + fm) * LDB + kk + quad * 8]);
                acc[j] = __builtin_amdgcn_mfma_f32_16x16x32_bf16(af, bf, acc[j], 0, 0, 0);
            }
        }
    }

    // epilogue: C/D layout col=lane&15, row=quad*4+reg. Tile 9 -> dump (pointer select, no branch).
    float* out = Cpart + (size_t)ks * (NAG * NB);
    #pragma unroll
    for (int j = 0; j < 5; ++j) {
        int nt = nhalf * 5 + j;
        int col = nt * 16 + fm;
        #pragma unroll
        for (int r = 0; r < 4; ++r) {
            int row = row0 + strip * 16 + quad * 4 + r;
            float* dst = (nt < 9) ? &out[(size_t)row * NB + col] : &dump[lane];
            *dst = acc[j][r];
        }
    }
#undef LOADAB
#undef STOREAB
}

// ---------------- Kernel 3: reduce partials, msg=sum/deg, actor MLP, dtype-adaptive ----------------
__global__ __launch_bounds__(256) void k3_actor(
    const float* __restrict__ h_f32,          // [8192][128]
    const float* __restrict__ Cpart,          // [NSPLIT][8192][144] fp32
    const void* __restrict__ W2,              // [256][128]
    const void* __restrict__ b2,              // [128]
    const void* __restrict__ W3,              // [128][16]
    const void* __restrict__ b3,              // [16]
    const int* __restrict__ flag,
    void* __restrict__ out)                   // [8192][16]
{
    __shared__ float comb[32][256];
    __shared__ float hid[32][132];
    __shared__ float inv_lds[32];
    const int t = threadIdx.x;
    const int abase = blockIdx.x * 32;
    const bool isf = (*flag != 0);
    const size_t PS = (size_t)NAG * NB;

    if (t < 32) {
        float deg = 0.f;
        #pragma unroll
        for (int s = 0; s < NSPLIT; ++s)
            deg += Cpart[s * PS + (size_t)(abase + t) * NB + 128];
        inv_lds[t] = 1.0f / fmaxf(deg, 1.0f);
    }
    __syncthreads();
    #pragma unroll
    for (int j = 0; j < 4; ++j) {
        int idx = j * 256 + t, a = idx >> 5, c = idx & 31;
        float4 v = *reinterpret_cast<const float4*>(h_f32 + (size_t)(abase + a) * 128 + c * 4);
        *reinterpret_cast<float4*>(&comb[a][c * 4]) = v;
    }
    #pragma unroll
    for (int j = 0; j < 4; ++j) {
        int idx = j * 256 + t, a = idx >> 5, c = idx & 31;
        float4 v = make_float4(0.f, 0.f, 0.f, 0.f);
        #pragma unroll
        for (int s = 0; s < NSPLIT; ++s) {
            float4 p = *reinterpret_cast<const float4*>(Cpart + s * PS + (size_t)(abase + a) * NB + c * 4);
            v.x += p.x; v.y += p.y; v.z += p.z; v.w += p.w;
        }
        float sc = inv_lds[a];
        v.x *= sc; v.y *= sc; v.z *= sc; v.w *= sc;
        *reinterpret_cast<float4*>(&comb[a][128 + c * 4]) = v;
    }
    __syncthreads();

    const int o = t & 127, half = t >> 7;
    float acc[16];
    if (isf) {
        const float* Wp = (const float*)W2;
        float bias = ((const float*)b2)[o];
        #pragma unroll
        for (int i = 0; i < 16; ++i) acc[i] = bias;
        for (int c0 = 0; c0 < 256; c0 += 8) {
            float w[8];
            #pragma unroll
            for (int j = 0; j < 8; ++j) w[j] = Wp[(c0 + j) * 128 + o];
            #pragma unroll
            for (int j = 0; j < 8; ++j)
                #pragma unroll
                for (int i = 0; i < 16; ++i)
                    acc[i] = fmaf(comb[half * 16 + i][c0 + j], w[j], acc[i]);
        }
    } else {
        const unsigned short* Wp = (const unsigned short*)W2;
        float bias = bf2f(((const unsigned short*)b2)[o]);
        #pragma unroll
        for (int i = 0; i < 16; ++i) acc[i] = bias;
        for (int c0 = 0; c0 < 256; c0 += 8) {
            float w[8];
            #pragma unroll
            for (int j = 0; j < 8; ++j) w[j] = bf2f(Wp[(c0 + j) * 128 + o]);
            #pragma unroll
            for (int j = 0; j < 8; ++j)
                #pragma unroll
                for (int i = 0; i < 16; ++i)
                    acc[i] = fmaf(comb[half * 16 + i][c0 + j], w[j], acc[i]);
        }
    }
    #pragma unroll
    for (int i = 0; i < 16; ++i)
        hid[half * 16 + i][o] = tanhf(acc[i]);
    __syncthreads();

    const int q = t & 15, ar = t >> 4;   // agents ar and ar+16
    float l0, l1;
    if (isf) {
        const float* Wp = (const float*)W3;
        l0 = ((const float*)b3)[q]; l1 = l0;
        #pragma unroll 4
        for (int oo = 0; oo < 128; ++oo) {
            float w = Wp[oo * 16 + q];
            l0 = fmaf(hid[ar][oo], w, l0);
            l1 = fmaf(hid[ar + 16][oo], w, l1);
        }
    } else {
        const unsigned short* Wp = (const unsigned short*)W3;
        l0 = bf2f(((const unsigned short*)b3)[q]); l1 = l0;
        #pragma unroll 4
        for (int oo = 0; oo < 128; ++oo) {
            float w = bf2f(Wp[oo * 16 + q]);
            l0 = fmaf(hid[ar][oo], w, l0);
            l1 = fmaf(hid[ar + 16][oo], w, l1);
        }
    }
    size_t i0 = (size_t)(abase + ar) * 16 + q;
    size_t i1 = (size_t)(abase + ar + 16) * 16 + q;
    if (isf) {
        ((float*)out)[i0] = l0;
        ((float*)out)[i1] = l1;
    } else {
        ((unsigned short*)out)[i0] = f2bf(l0);
        ((unsigned short*)out)[i1] = f2bf(l1);
    }
}

extern "C" void kernel_launch(void* const* d_in, const int* in_sizes, int n_in,
                              void* d_out, int out_size, void* d_ws, size_t ws_size,
                              hipStream_t stream) {
    const void* obs = d_in[0];
    const int*  adj = (const int*)d_in[1];
    const void* W1  = d_in[2];
    const void* b1  = d_in[3];
    const void* W2  = d_in[4];
    const void* b2  = d_in[5];
    const void* W3  = d_in[6];
    const void* b3  = d_in[7];

    char* ws = (char*)d_ws;
    unsigned short* hT = (unsigned short*)(ws);                 // 2,359,296 B
    float* h_f32 = (float*)(ws + 2359296);                      // 4,194,304 B
    float* Cpart = (float*)(ws + 2359296 + 4194304);            // 4 x 4,718,592 = 18,874,368 B
    int*   flag  = (int*)(ws + 25427968);                       // 4 B
    float* dump  = (float*)(ws + 25428224);                     // 256 B scrap (tile-9 stores)

    hipLaunchKernelGGL(k0_init, dim3(1), dim3(64), 0, stream, flag, (const unsigned short*)W1);
    hipLaunchKernelGGL(k1_encode, dim3(256), dim3(256), 0, stream, obs, W1, b1, flag, h_f32, hT);
    hipLaunchKernelGGL(k2_msggemm, dim3(512), dim3(512), 0, stream, adj, hT, Cpart, dump);
    hipLaunchKernelGGL(k3_actor, dim3(256), dim3(256), 0, stream, h_f32, Cpart, W2, b2, W3, b3, flag, d_out);
}